// Round 1
// baseline (281.754 us; speedup 1.0000x reference)
//
#include <hip/hip_runtime.h>

typedef __attribute__((ext_vector_type(8))) short short8;
typedef __attribute__((ext_vector_type(4))) float f32x4;

#define DEVI static __device__ __forceinline__

constexpr int NB   = 4;     // batch
constexpr int NH   = 2;     // heads
constexpr int SEQ  = 2048;  // Lq = Lk
constexpr int DM   = 512;   // d_model
constexpr int DKV  = 64;    // d_k = d_v
constexpr int HDIM = 128;   // NH * DKV

DEVI unsigned short f2bf(float f) {
    union { float f; unsigned u; } v; v.f = f;
    unsigned r = v.u + 0x7FFFu + ((v.u >> 16) & 1u);
    return (unsigned short)(r >> 16);
}
DEVI float bf2f(unsigned short s) {
    union { unsigned u; float f; } v; v.u = ((unsigned)s) << 16; return v.f;
}
// async global->LDS, 16B per lane. LDS dest = wave-uniform base + lane*16.
DEVI void async16(const void* g, void* l) {
    __builtin_amdgcn_global_load_lds(
        (const __attribute__((address_space(1))) unsigned int*)g,
        (__attribute__((address_space(3))) unsigned int*)l, 16, 0, 0);
}

// ---------------------------------------------------------------------------
// k_prep: weights f32 -> bf16, transposed so MFMA B-operand rows are K-contig.
__global__ __launch_bounds__(256) void k_prep(
    const float* __restrict__ Wq, const float* __restrict__ Wk,
    const float* __restrict__ Wv, const float* __restrict__ Wo,
    unsigned short* __restrict__ Wqt, unsigned short* __restrict__ Wkt,
    unsigned short* __restrict__ Wvt, unsigned short* __restrict__ Wot) {
    int id = blockIdx.x * 256 + threadIdx.x;        // 0 .. 262143
    int which = id >> 16;
    int rem = id & 65535;
    if (which < 3) {
        const float* W = which == 0 ? Wq : (which == 1 ? Wk : Wv);
        unsigned short* Wt = which == 0 ? Wqt : (which == 1 ? Wkt : Wvt);
        int n = rem >> 9, k = rem & 511;            // dst [128][512]
        Wt[rem] = f2bf(W[k * HDIM + n]);
    } else {
        int n = rem >> 7, k = rem & 127;            // dst [512][128]
        Wot[rem] = f2bf(Wo[k * DM + n]);
    }
}

// ---------------------------------------------------------------------------
// k_proj: X[8192,512] @ W[512,128] + b  ->  per-head bf16 layouts.
// LDS tiles are XOR-swizzled (slot ^= row&7 at 16B granularity) so all
// ds_read_b128 operand reads are bank-conflict-free. lB is staged with
// pre-swizzled GLOBAL source (LDS dest stays linear for global_load_lds).
__global__ __launch_bounds__(256) void k_proj(
    const float* __restrict__ Qg, const float* __restrict__ Kg, const float* __restrict__ Vg,
    const unsigned short* __restrict__ Wqt, const unsigned short* __restrict__ Wkt,
    const unsigned short* __restrict__ Wvt,
    const float* __restrict__ bq, const float* __restrict__ bk, const float* __restrict__ bv,
    unsigned short* __restrict__ qs, unsigned short* __restrict__ kb,
    unsigned short* __restrict__ vt) {
    __shared__ unsigned short lA[64 * 64];
    __shared__ unsigned short lB[128 * 64];

    const int y = blockIdx.y;
    const float* X = y == 0 ? Qg : (y == 1 ? Kg : Vg);
    const unsigned short* Wt = y == 0 ? Wqt : (y == 1 ? Wkt : Wvt);
    const float* bias = y == 0 ? bq : (y == 1 ? bk : bv);
    const float scal = y == 0 ? 0.125f : 1.0f;   // fold 1/sqrt(dk) into q
    const int row0 = blockIdx.x * 64;
    const int tid = threadIdx.x, lane = tid & 63, wv = tid >> 6;
    const int l16 = lane & 15, lq4 = lane >> 4;
    const int wr = wv >> 1, wc = wv & 1;

    f32x4 acc[2][4];
    #pragma unroll
    for (int i = 0; i < 2; ++i)
        #pragma unroll
        for (int j = 0; j < 4; ++j) acc[i][j] = f32x4{0.f, 0.f, 0.f, 0.f};

    const int arow = tid >> 2, ac0 = (tid & 3) * 16;

    for (int kc = 0; kc < 8; ++kc) {
        {
            const float* src = X + (size_t)(row0 + arow) * DM + kc * 64 + ac0;
            #pragma unroll
            for (int i = 0; i < 4; ++i) {
                float4 v = *(const float4*)(src + 4 * i);
                unsigned p0 = (unsigned)f2bf(v.x) | ((unsigned)f2bf(v.y) << 16);
                unsigned p1 = (unsigned)f2bf(v.z) | ((unsigned)f2bf(v.w) << 16);
                int slot = ((tid & 3) * 2 + (i >> 1)) ^ (arow & 7);
                char* d = (char*)lA + arow * 128 + slot * 16 + (i & 1) * 8;
                *(unsigned*)d = p0;
                *(unsigned*)(d + 4) = p1;
            }
        }
        #pragma unroll
        for (int c = 0; c < 4; ++c) {
            int chunk = wv * 4 + c;
            int n = chunk * 8 + (lane >> 3);
            int gslot = (lane & 7) ^ (n & 7);
            const void* g = (const char*)Wt + ((size_t)n * DM + kc * 64) * 2 + gslot * 16;
            void* l = (char*)lB + chunk * 1024 + lane * 16;
            async16(g, l);
        }
        __syncthreads();

        #pragma unroll
        for (int ks = 0; ks < 2; ++ks) {
            short8 a[2], b[4];
            #pragma unroll
            for (int mt = 0; mt < 2; ++mt) {
                int m = wr * 32 + mt * 16 + l16;
                unsigned ao = (unsigned)(m * 128 + ks * 64 + lq4 * 16) ^ ((unsigned)(m & 7) << 4);
                a[mt] = *(const short8*)((const char*)lA + ao);
            }
            #pragma unroll
            for (int nt = 0; nt < 4; ++nt) {
                int n = wc * 64 + nt * 16 + l16;
                unsigned bo2 = (unsigned)(n * 128 + ks * 64 + lq4 * 16) ^ ((unsigned)(n & 7) << 4);
                b[nt] = *(const short8*)((const char*)lB + bo2);
            }
            #pragma unroll
            for (int mt = 0; mt < 2; ++mt)
                #pragma unroll
                for (int nt = 0; nt < 4; ++nt)
                    acc[mt][nt] = __builtin_amdgcn_mfma_f32_16x16x32_bf16(
                        a[mt], b[nt], acc[mt][nt], 0, 0, 0);
        }
        __syncthreads();
    }

    if (y < 2) {
        unsigned short* dstp = (y == 0) ? qs : kb;
        #pragma unroll
        for (int mt = 0; mt < 2; ++mt)
            #pragma unroll
            for (int nt = 0; nt < 4; ++nt) {
                int col = wc * 64 + nt * 16 + l16;
                float bb = bias[col];
                int h = col >> 6, d = col & 63;
                #pragma unroll
                for (int r = 0; r < 4; ++r) {
                    int row = row0 + wr * 32 + mt * 16 + lq4 * 4 + r;
                    int b = row >> 11, pos = row & 2047;
                    float val = (acc[mt][nt][r] + bb) * scal;
                    dstp[((size_t)(b * NH + h) * SEQ + pos) * DKV + d] = f2bf(val);
                }
            }
    } else {
        #pragma unroll
        for (int mt = 0; mt < 2; ++mt)
            #pragma unroll
            for (int nt = 0; nt < 4; ++nt) {
                int col = wc * 64 + nt * 16 + l16;
                float bb = bias[col];
                #pragma unroll
                for (int r = 0; r < 4; ++r) {
                    int mrow = wr * 32 + mt * 16 + lq4 * 4 + r;
                    lB[col * 64 + mrow] = f2bf(acc[mt][nt][r] + bb);
                }
            }
        __syncthreads();
        int c = tid >> 1, mp = (tid & 1) * 32;
        int b = row0 >> 11, kpos0 = row0 & 2047;
        int h = c >> 6, d = c & 63;
        unsigned short* dst = vt + ((size_t)(b * NH + h) * DKV + d) * SEQ + kpos0 + mp;
        const unsigned short* srcl = &lB[c * 64 + mp];
        #pragma unroll
        for (int i = 0; i < 4; ++i)
            *(uint4*)(dst + 8 * i) = *(const uint4*)(srcl + 8 * i);
    }
}

// ---------------------------------------------------------------------------
// k_fused: one block per (bh, 32-row q-tile). Holds the full 32x2048 score
// row in 128KB XOR-swizzled LDS (bf16).
//   sweep1: QK^T (K frags straight from L2) -> tanh/mask -> sAttn + exp-sums
//   L = log(sum) in-block
//   finalize: attn f32 = bf2f(sAttn) - L -> global (written ONCE, coalesced);
//             sAttn rewritten as bf16(s - L) for PV
//   PV: out = attn @ V, V frags straight from L2. No staging barriers.
// grid 512 = 8 bh * 64 qtiles, XCD-swizzled so each XCD owns one bh (K/V L2-resident).
__global__ __launch_bounds__(512) void k_fused(
    const unsigned short* __restrict__ qs, const unsigned short* __restrict__ kb,
    const unsigned short* __restrict__ vt, const int* __restrict__ maskg,
    float* __restrict__ attnG, unsigned short* __restrict__ outh) {
    __shared__ unsigned short sAttn[32 * 2048];   // 128 KB, swizzled: byte ^= (row&7)<<4
    __shared__ float lsum[4][32];
    __shared__ float lL[32];

    const int wg = blockIdx.x;
    const int swz = (wg & 7) * 64 + (wg >> 3);    // XCD x -> bh x
    const int bh = swz >> 6;
    const int qt = swz & 63;
    const int qbase = qt * 32;
    const int b = bh >> 1, h = bh & 1;
    const int tid = threadIdx.x, lane = tid & 63, wv = tid >> 6;  // 8 waves
    const int l16 = lane & 15, lq4 = lane >> 4;
    const int wr = wv >> 2, wc = wv & 3;          // wr: q 16-row tile; wc: 16-col group

    // Q fragments: A rows = wr*16 + l16
    const unsigned short* qrow =
        qs + ((size_t)bh * SEQ + qbase + wr * 16 + l16) * DKV + lq4 * 8;
    short8 aq0 = *(const short8*)qrow;
    short8 aq1 = *(const short8*)(qrow + 32);

    const unsigned short* kfrag =
        kb + ((size_t)bh * SEQ + wc * 16 + l16) * DKV + lq4 * 8;
    const int* mrow = maskg + b * SEQ + wc * 16 + l16;

    const int srow_q = wr * 16 + lq4 * 4;         // score D-row base (+r)
    const int cbase = wc * 16 + l16;              // score D-col (k-local, per kt +64)

    float sums[4] = {0.f, 0.f, 0.f, 0.f};

    #pragma unroll 2
    for (int kt = 0; kt < 32; ++kt) {
        short8 b0 = *(const short8*)(kfrag + (size_t)kt * 4096);
        short8 b1 = *(const short8*)(kfrag + (size_t)kt * 4096 + 32);
        int mv = mrow[kt * 64];
        f32x4 acc = f32x4{0.f, 0.f, 0.f, 0.f};
        acc = __builtin_amdgcn_mfma_f32_16x16x32_bf16(aq0, b0, acc, 0, 0, 0);
        acc = __builtin_amdgcn_mfma_f32_16x16x32_bf16(aq1, b1, acc, 0, 0, 0);
        int col = kt * 64 + cbase;
        #pragma unroll
        for (int r = 0; r < 4; ++r) {
            float x = acc[r];                               // q.k / 8
            float e2 = __expf(2.f * x);
            float s10 = 10.f - 20.f * __builtin_amdgcn_rcpf(1.f + e2);
            float s = mv ? -10.f : s10;
            sums[r] += __expf(s);
            int row = srow_q + r;
            unsigned bo = (unsigned)(row * 4096 + col * 2) ^ ((unsigned)(row & 7) << 4);
            *(unsigned short*)((char*)sAttn + bo) = f2bf(s);
        }
    }

    // row sums -> L (rows covered by 4 wc-waves x 16 l16 lanes each)
    #pragma unroll
    for (int r = 0; r < 4; ++r) {
        float v = sums[r];
        v += __shfl_xor(v, 1); v += __shfl_xor(v, 2);
        v += __shfl_xor(v, 4); v += __shfl_xor(v, 8);
        if (l16 == 0) lsum[wc][srow_q + r] = v;
    }
    __syncthreads();
    if (tid < 32)
        lL[tid] = __logf(lsum[0][tid] + lsum[1][tid] + lsum[2][tid] + lsum[3][tid]);
    __syncthreads();

    // finalize: attn f32 out (once, coalesced 512B/wave-row) + rewrite s-L into sAttn
    {
        const int row = tid >> 4;
        const int cb = (tid & 15) * 8;
        const float Lv = lL[row];
        float* gdst = attnG + ((size_t)bh * SEQ + qbase + row) * SEQ;
        const unsigned rbase = (unsigned)(row * 4096);
        const unsigned rxor = (unsigned)(row & 7) << 4;
        #pragma unroll
        for (int j = 0; j < 16; ++j) {
            int c = cb + j * 128;
            unsigned bo = (rbase + (unsigned)(c * 2)) ^ rxor;
            short8 v = *(const short8*)((const char*)sAttn + bo);
            float fv[8];
            #pragma unroll
            for (int t = 0; t < 8; ++t) fv[t] = bf2f((unsigned short)v[t]) - Lv;
            float4 fa, fb;
            fa.x = fv[0]; fa.y = fv[1]; fa.z = fv[2]; fa.w = fv[3];
            fb.x = fv[4]; fb.y = fv[5]; fb.z = fv[6]; fb.w = fv[7];
            *(float4*)(gdst + c) = fa;
            *(float4*)(gdst + c + 4) = fb;
            short8 w;
            #pragma unroll
            for (int t = 0; t < 8; ++t) w[t] = (short)f2bf(fv[t]);
            *(short8*)((char*)sAttn + bo) = w;
        }
    }
    __syncthreads();

    // PV: out[q][d] += attn[q][k] * V[k][d]; B frags (V^T rows) straight from L2.
    const unsigned short* vfrag =
        vt + ((size_t)bh * DKV + wc * 16 + l16) * SEQ + lq4 * 8;
    const int arow = wr * 16 + l16;
    const unsigned abase = (unsigned)(arow * 4096);
    const unsigned axor = (unsigned)(arow & 7) << 4;
    f32x4 o = f32x4{0.f, 0.f, 0.f, 0.f};
    #pragma unroll 4
    for (int ks = 0; ks < 64; ++ks) {
        short8 af = *(const short8*)((const char*)sAttn +
                                     ((abase + (unsigned)(ks * 64 + lq4 * 16)) ^ axor));
        short8 vf = *(const short8*)(vfrag + ks * 32);
        o = __builtin_amdgcn_mfma_f32_16x16x32_bf16(af, vf, o, 0, 0, 0);
    }

    #pragma unroll
    for (int r = 0; r < 4; ++r) {
        size_t orow = (size_t)b * SEQ + qbase + wr * 16 + lq4 * 4 + r;
        outh[orow * HDIM + h * DKV + wc * 16 + l16] = f2bf(o[r]);
    }
}

// ---------------------------------------------------------------------------
// k_oproj: out = outh[8192,128] @ Wo[128,512] + bo.  grid (64, 4).
// Staging pre-swizzled at the global source; reads swizzled -> conflict-free.
__global__ __launch_bounds__(256) void k_oproj(
    const unsigned short* __restrict__ outh, const unsigned short* __restrict__ Wot,
    const float* __restrict__ bo, float* __restrict__ outG) {
    __shared__ unsigned short lA2[128 * 128];
    __shared__ unsigned short lB2[128 * 128];
    const int row0 = blockIdx.x * 128, col0 = blockIdx.y * 128;
    const int tid = threadIdx.x, lane = tid & 63, wv = tid >> 6;
    const int l16 = lane & 15, lq4 = lane >> 4;
    const int wr = wv >> 1, wc = wv & 1;

    #pragma unroll
    for (int c = 0; c < 8; ++c) {
        int chunk = wv * 8 + c;
        int row = chunk * 4 + (lane >> 4);
        int gslot = (lane & 15) ^ (row & 7);
        async16((const char*)outh + ((size_t)(row0 + row)) * 256 + gslot * 16,
                (char*)lA2 + chunk * 1024 + lane * 16);
    }
    #pragma unroll
    for (int c = 0; c < 8; ++c) {
        int chunk = wv * 8 + c;
        int row = chunk * 4 + (lane >> 4);
        int gslot = (lane & 15) ^ (row & 7);
        async16((const char*)Wot + ((size_t)(col0 + row)) * 256 + gslot * 16,
                (char*)lB2 + chunk * 1024 + lane * 16);
    }
    __syncthreads();

    f32x4 acc[4][4];
    #pragma unroll
    for (int mt = 0; mt < 4; ++mt)
        #pragma unroll
        for (int nt = 0; nt < 4; ++nt) acc[mt][nt] = f32x4{0.f, 0.f, 0.f, 0.f};

    #pragma unroll
    for (int ks = 0; ks < 4; ++ks) {
        short8 a[4], bfr[4];
        #pragma unroll
        for (int mt = 0; mt < 4; ++mt) {
            int m = wr * 64 + mt * 16 + l16;
            unsigned ao = (unsigned)(m * 256 + ks * 64 + lq4 * 16) ^ ((unsigned)(m & 7) << 4);
            a[mt] = *(const short8*)((const char*)lA2 + ao);
        }
        #pragma unroll
        for (int nt = 0; nt < 4; ++nt) {
            int n = wc * 64 + nt * 16 + l16;
            unsigned bo2 = (unsigned)(n * 256 + ks * 64 + lq4 * 16) ^ ((unsigned)(n & 7) << 4);
            bfr[nt] = *(const short8*)((const char*)lB2 + bo2);
        }
        #pragma unroll
        for (int mt = 0; mt < 4; ++mt)
            #pragma unroll
            for (int nt = 0; nt < 4; ++nt)
                acc[mt][nt] = __builtin_amdgcn_mfma_f32_16x16x32_bf16(
                    a[mt], bfr[nt], acc[mt][nt], 0, 0, 0);
    }

    #pragma unroll
    for (int nt = 0; nt < 4; ++nt) {
        int col = col0 + wc * 64 + nt * 16 + l16;
        float bb = bo[col];
        #pragma unroll
        for (int mt = 0; mt < 4; ++mt)
            #pragma unroll
            for (int r = 0; r < 4; ++r) {
                int row = row0 + wr * 64 + mt * 16 + lq4 * 4 + r;
                outG[(size_t)row * DM + col] = acc[mt][nt][r] + bb;
            }
    }
}

// ---------------------------------------------------------------------------
extern "C" void kernel_launch(void* const* d_in, const int* in_sizes, int n_in,
                              void* d_out, int out_size, void* d_ws, size_t ws_size,
                              hipStream_t stream) {
    (void)in_sizes; (void)n_in; (void)out_size; (void)ws_size;
    const float* Qg = (const float*)d_in[0];
    const float* Kg = (const float*)d_in[1];
    const float* Vg = (const float*)d_in[2];
    const int*   maskg = (const int*)d_in[3];
    const float* Wq = (const float*)d_in[4];
    const float* bq = (const float*)d_in[5];
    const float* Wk = (const float*)d_in[6];
    const float* bk = (const float*)d_in[7];
    const float* Wv = (const float*)d_in[8];
    const float* bv = (const float*)d_in[9];
    const float* Wo = (const float*)d_in[10];
    const float* bo = (const float*)d_in[11];

    char* ws = (char*)d_ws;
    unsigned short* qs   = (unsigned short*)(ws);                    // 2 MB
    unsigned short* kb   = (unsigned short*)(ws + (4  << 20));       // 2 MB
    unsigned short* vt   = (unsigned short*)(ws + (8  << 20));       // 2 MB
    unsigned short* outh = (unsigned short*)(ws + (28 << 20));       // 2 MB
    unsigned short* Wqt  = (unsigned short*)(ws + (30 << 20) + 262144);
    unsigned short* Wkt  = (unsigned short*)((char*)Wqt + 131072);
    unsigned short* Wvt  = (unsigned short*)((char*)Wkt + 131072);
    unsigned short* Wot  = (unsigned short*)((char*)Wvt + 131072);

    float* outG  = (float*)d_out;
    float* attnG = outG + (size_t)NB * SEQ * DM;

    hipLaunchKernelGGL(k_prep, dim3(1024), dim3(256), 0, stream,
                       Wq, Wk, Wv, Wo, Wqt, Wkt, Wvt, Wot);
    hipLaunchKernelGGL(k_proj, dim3(128, 3), dim3(256), 0, stream,
                       Qg, Kg, Vg, Wqt, Wkt, Wvt, bq, bk, bv, qs, kb, vt);
    hipLaunchKernelGGL(k_fused, dim3(512), dim3(512), 0, stream,
                       qs, kb, vt, maskg, attnG, outh);
    hipLaunchKernelGGL(k_oproj, dim3(64, 4), dim3(256), 0, stream, outh, Wot, bo, outG);
}